// Round 13
// baseline (856.064 us; speedup 1.0000x reference)
//
#include <hip/hip_runtime.h>
#include <hip/hip_fp16.h>

#define EPSBN 1e-5f
#define SH 7          // bucket = dst >> SH  (128 nodes per bucket)
#define CHUNK 16384   // edges per sort chunk
#define SCANB 256     // scan blocks
#define MAXP 8        // node-pairs per wave in k_gall

// ------------------------------------------------------- bucketed count sort
__launch_bounds__(1024)
__global__ void k_hist(const int* __restrict__ dst, int* __restrict__ hist,
                       int E, int C, int NB) {
    __shared__ int h[1024];
    const int tid = threadIdx.x, c = blockIdx.x;
    for (int i = tid; i < NB; i += 1024) h[i] = 0;
    __syncthreads();
    const int e0 = c * CHUNK, e1 = min(e0 + CHUNK, E);
    for (int e = e0 + tid; e < e1; e += 1024) atomicAdd(&h[dst[e] >> SH], 1);
    __syncthreads();
    for (int b = tid; b < NB; b += 1024) hist[b * C + c] = h[b];
}

__launch_bounds__(256)
__global__ void k_scanA(const int* __restrict__ hist, int* __restrict__ bsum, int M) {
    __shared__ int part[256];
    const int b = blockIdx.x, t = threadIdx.x;
    const int seg = (M + SCANB - 1) / SCANB;
    const int lo = b * seg, hi = min(lo + seg, M);
    int s = 0;
    for (int i = lo + t; i < hi; i += 256) s += hist[i];
    part[t] = s;
    __syncthreads();
    for (int d = 128; d > 0; d >>= 1) {
        if (t < d) part[t] += part[t + d];
        __syncthreads();
    }
    if (t == 0) bsum[b] = part[0];
}

__launch_bounds__(256)
__global__ void k_scanB(int* __restrict__ bsum, float* __restrict__ st,
                        float* __restrict__ poolsum, float* __restrict__ counts, int G) {
    __shared__ int sh[256];
    const int t = threadIdx.x;
    sh[t] = bsum[t];
    __syncthreads();
    for (int d = 1; d < 256; d <<= 1) {
        int v = (t >= d) ? sh[t - d] : 0;
        __syncthreads();
        sh[t] += v;
        __syncthreads();
    }
    bsum[t] = (t == 0) ? 0 : sh[t - 1];
    for (int i = t; i < 3 * 128; i += 256) st[i] = 0.f;
    for (int i = t; i < G * 64; i += 256) poolsum[i] = 0.f;
    for (int i = t; i < G; i += 256) counts[i] = 0.f;
}

__launch_bounds__(256)
__global__ void k_scanC(int* __restrict__ hist, const int* __restrict__ bsum,
                        int* __restrict__ off, int M, int E, int N) {
    __shared__ int part[256];
    const int b = blockIdx.x, t = threadIdx.x;
    const int seg = (M + SCANB - 1) / SCANB;
    const int lo = b * seg, hi = min(lo + seg, M);
    const int per = (seg + 255) >> 8;
    const int tl = lo + t * per, th = min(tl + per, hi);
    int s = 0;
    for (int i = tl; i < th; ++i) s += hist[i];
    part[t] = s;
    __syncthreads();
    for (int d = 1; d < 256; d <<= 1) {
        int v = (t >= d) ? part[t - d] : 0;
        __syncthreads();
        part[t] += v;
        __syncthreads();
    }
    int run = bsum[b] + ((t == 0) ? 0 : part[t - 1]);
    for (int i = tl; i < th; ++i) {
        int v = hist[i];
        hist[i] = run;
        run += v;
    }
    if (b == 0 && t == 0) off[N] = E;
}

__launch_bounds__(1024)
__global__ void k_sort(const int* __restrict__ src, const int* __restrict__ dst,
                       const int* __restrict__ hist, int* __restrict__ spk,
                       int E, int C, int NB) {
    __shared__ int cur[1024];
    const int tid = threadIdx.x, c = blockIdx.x;
    for (int b = tid; b < NB; b += 1024) cur[b] = hist[b * C + c];
    __syncthreads();
    const int e0 = c * CHUNK, e1 = min(e0 + CHUNK, E);
    for (int e = e0 + tid; e < e1; e += 1024) {
        const int d = dst[e];
        const int pos = atomicAdd(&cur[d >> SH], 1);
        spk[pos] = ((d & 127) << 18) | src[e];
    }
}

// S4: per bucket -> per-(node,band) counts, off[], bnd[], dis[], x0s4, eda
// grouped by (node, band). band = min(3, src*invw) -- pure-locality split.
__launch_bounds__(256)
__global__ void k_csr(const int* __restrict__ spk, const int* __restrict__ hist,
                      const float* __restrict__ x0, int* __restrict__ off,
                      int* __restrict__ bnd, float* __restrict__ dis,
                      float4* __restrict__ x0s4, int* __restrict__ eda,
                      int E, int C, int NB, int N, float invw) {
    __shared__ int cnt4[512];
    __shared__ int cnt_l[128], scn[128];
    const int tid = threadIdx.x, b = blockIdx.x;
    const int node0 = b << SH;
    const int nloc = min(128, N - node0);
    const int ebeg = hist[b * C];
    const int eend = (b + 1 < NB) ? hist[(b + 1) * C] : E;
    for (int i = tid; i < 512; i += 256) cnt4[i] = 0;
    __syncthreads();
    for (int e = ebeg + tid; e < eend; e += 256) {
        const int p = spk[e];
        const int loc = p >> 18;
        const int s = p & 0x3FFFF;
        const int band = min(3, (int)((float)s * invw));
        atomicAdd(&cnt4[(loc << 2) | band], 1);
    }
    __syncthreads();
    if (tid < 128) {
        cnt_l[tid] = cnt4[tid << 2] + cnt4[(tid << 2) | 1] + cnt4[(tid << 2) | 2] +
                     cnt4[(tid << 2) | 3];
        scn[tid] = cnt_l[tid];
    }
    __syncthreads();
    for (int d = 1; d < 128; d <<= 1) {
        int v = 0;
        if (tid < 128 && tid >= d) v = scn[tid - d];
        __syncthreads();
        if (tid < 128) scn[tid] += v;
        __syncthreads();
    }
    if (tid < nloc) {
        const int start = scn[tid] - cnt_l[tid];
        const int i = node0 + tid;
        const float d = rsqrtf((float)cnt_l[tid] + 1.0f);
        off[i] = ebeg + start;
        dis[i] = d;
        x0s4[i] = make_float4(d * x0[3 * i], d * x0[3 * i + 1], d * x0[3 * i + 2], 0.f);
        int run = start;
#pragma unroll
        for (int bb = 0; bb < 4; ++bb) {
            const int cc = cnt4[(tid << 2) | bb];
            bnd[((long)i << 2) | bb] = ebeg + run;
            cnt4[(tid << 2) | bb] = run;
            run += cc;
        }
    }
    __syncthreads();
    for (int e = ebeg + tid; e < eend; e += 256) {
        const int p = spk[e];
        const int loc = p >> 18;
        const int s = p & 0x3FFFF;
        const int band = min(3, (int)((float)s * invw));
        const int r = atomicAdd(&cnt4[(loc << 2) | band], 1);
        eda[ebeg + r] = s;
    }
}

// ------------------------- layer 0: gather(3ch) + @W0 + BN stats, all fused
__launch_bounds__(256)
__global__ void k_gl0(const int* __restrict__ off, const int* __restrict__ eda,
                      const float* __restrict__ dis, const float4* __restrict__ x0s4,
                      const float* __restrict__ W0, __half* __restrict__ bufh,
                      float* __restrict__ st, int N) {
    __shared__ float Ws[192];
    __shared__ float ls[256], lq[256];
    const int tid = threadIdx.x;
    const int lane = tid & 63, wv = tid >> 6;
    for (int i = tid; i < 192; i += 256) Ws[i] = W0[i];
    __syncthreads();
    const int nw = gridDim.x * 4;
    float s = 0.f, q = 0.f;
    for (int w = blockIdx.x * 4 + wv; w < N; w += nw) {
        const int e0 = off[w], e1 = off[w + 1];
        float a0 = 0.f, a1 = 0.f, a2 = 0.f;
        for (int e = e0 + lane; e < e1; e += 64) {
            float4 v = x0s4[eda[e]];
            a0 += v.x;
            a1 += v.y;
            a2 += v.z;
        }
#pragma unroll
        for (int d = 32; d; d >>= 1) {
            a0 += __shfl_xor(a0, d);
            a1 += __shfl_xor(a1, d);
            a2 += __shfl_xor(a2, d);
        }
        const float4 sv = x0s4[w];
        const float dw = dis[w];
        const float z0 = dw * (a0 + sv.x), z1 = dw * (a1 + sv.y), z2 = dw * (a2 + sv.z);
        const float val = z0 * Ws[lane] + z1 * Ws[64 + lane] + z2 * Ws[128 + lane];
        bufh[((long)w << 6) + lane] = __float2half(val);
        s += val;
        q = fmaf(val, val, q);
    }
    ls[tid] = s;
    lq[tid] = q;
    __syncthreads();
    if (tid < 64) {
        s = ls[lane] + ls[lane + 64] + ls[lane + 128] + ls[lane + 192];
        q = lq[lane] + lq[lane + 64] + lq[lane + 128] + lq[lane + 192];
        unsafeAtomicAdd(&st[lane], s);
        unsafeAtomicAdd(&st[64 + lane], q);
    }
}

// --------------------------------------------------- fused (BN+ReLU) + linear
__launch_bounds__(256)
__global__ void k_linear(const __half* __restrict__ X, const float* __restrict__ W,
                         const float* __restrict__ st, const float* __restrict__ g,
                         const float* __restrict__ be, const float* __restrict__ dis,
                         __half* __restrict__ hp, int N) {
    __shared__ float Ws[64 * 64];
    __shared__ float Xs[32 * 64];
    __shared__ float scs[64], shs[64];
    const int tid = threadIdx.x;
    if (tid < 64) {
        const float inv = 1.0f / (float)N;
        const float m = st[tid] * inv;
        const float v = st[64 + tid] * inv - m * m;
        const float sc = g[tid] * rsqrtf(v + EPSBN);
        scs[tid] = sc;
        shs[tid] = fmaf(-m, sc, be[tid]);
    }
    for (int i = tid; i < 64 * 64; i += 256) Ws[i] = W[i];
    __syncthreads();
    const int c = tid & 63, wv = tid >> 6;
    for (int r0 = blockIdx.x * 32; r0 < N; r0 += gridDim.x * 32) {
        for (int i = tid; i < 32 * 32; i += 256) {
            const int r = i >> 5, c2 = i & 31;
            const int row = r0 + r;
            float2 f = {0.f, 0.f};
            if (row < N) {
                const __half2 hv = ((const __half2*)X)[((long)row << 5) + c2];
                f = __half22float2(hv);
            }
            const int ch = c2 * 2;
            Xs[r * 64 + ch] = fmaxf(fmaf(f.x, scs[ch], shs[ch]), 0.f);
            Xs[r * 64 + ch + 1] = fmaxf(fmaf(f.y, scs[ch + 1], shs[ch + 1]), 0.f);
        }
        __syncthreads();
        for (int rr = 0; rr < 8; ++rr) {
            const int r = wv * 8 + rr;
            const int row = r0 + r;
            if (row < N) {
                float acc = 0.f;
#pragma unroll
                for (int k = 0; k < 64; ++k) acc = fmaf(Xs[r * 64 + k], Ws[k * 64 + c], acc);
                hp[(long)row * 64 + c] = __float2half(acc * dis[row]);
            }
        }
        __syncthreads();
    }
}

// --------------------- banded gather, band-outer, register accumulators
// each wave owns MAXP node-pairs; accA/accB persist in VGPRs across bands.
// All blocks co-resident -> all waves process band b together -> hp window
// (N/4 rows = 3.2 MB) is L2-resident during band b. No accf buffer.
__launch_bounds__(256)
__global__ void k_gall(const int* __restrict__ off, const int* __restrict__ bnd,
                       const int* __restrict__ eda, const float* __restrict__ dis,
                       const __half* __restrict__ hp, __half* __restrict__ bufh,
                       float* __restrict__ st, int N) {
    __shared__ int els[4][2][64];
    __shared__ float ls[256], ls2[256];
    const int lane = threadIdx.x & 63;
    const int wv = threadIdx.x >> 6;
    const int w = blockIdx.x * 4 + wv;
    const int P = (N + 1) >> 1;
    const int p0 = w * MAXP;
    float accA[MAXP], accB[MAXP];
#pragma unroll
    for (int i = 0; i < MAXP; ++i) {
        const int p = p0 + i;
        accA[i] = (p < P) ? __half2float(hp[((long)p << 6) + lane]) : 0.f;
        const int wB = p + P;
        accB[i] = (p < P && wB < N) ? __half2float(hp[((long)wB << 6) + lane]) : 0.f;
    }
    for (int band = 0; band < 4; ++band) {
#pragma unroll
        for (int i = 0; i < MAXP; ++i) {
            const int p = p0 + i;
            if (p >= P) continue;
            const int wA = p, wB = p + P;
            const bool hasB = (wB < N);
            const int a0o = bnd[((long)wA << 2) | band];
            const int aend = (band == 3) ? off[wA + 1] : bnd[((long)wA << 2) | (band + 1)];
            const int nA = aend - a0o;
            int b0o = 0, nB = 0;
            if (hasB) {
                b0o = bnd[((long)wB << 2) | band];
                const int bend = (band == 3) ? off[wB + 1] : bnd[((long)wB << 2) | (band + 1)];
                nB = bend - b0o;
            }
            if ((nA | nB) == 0) continue;
            float tA0 = 0.f, tA1 = 0.f, tA2 = 0.f, tA3 = 0.f;
            float tB0 = 0.f, tB1 = 0.f, tB2 = 0.f, tB3 = 0.f;
            const int nmax = nA > nB ? nA : nB;
            for (int base = 0; base < nmax; base += 64) {
                if (base + lane < nA) els[wv][0][lane] = eda[a0o + base + lane];
                if (base + lane < nB) els[wv][1][lane] = eda[b0o + base + lane];
                int mA = nA - base;
                mA = mA < 0 ? 0 : (mA > 64 ? 64 : mA);
                int mB = nB - base;
                mB = mB < 0 ? 0 : (mB > 64 ? 64 : mB);
                const int mc = mA < mB ? mA : mB;
                int j = 0;
                for (; j + 4 <= mc; j += 4) {
                    const int sa0 = els[wv][0][j + 0], sa1 = els[wv][0][j + 1];
                    const int sa2 = els[wv][0][j + 2], sa3 = els[wv][0][j + 3];
                    const int sb0 = els[wv][1][j + 0], sb1 = els[wv][1][j + 1];
                    const int sb2 = els[wv][1][j + 2], sb3 = els[wv][1][j + 3];
                    tA0 += __half2float(hp[(long)sa0 * 64 + lane]);
                    tA1 += __half2float(hp[(long)sa1 * 64 + lane]);
                    tA2 += __half2float(hp[(long)sa2 * 64 + lane]);
                    tA3 += __half2float(hp[(long)sa3 * 64 + lane]);
                    tB0 += __half2float(hp[(long)sb0 * 64 + lane]);
                    tB1 += __half2float(hp[(long)sb1 * 64 + lane]);
                    tB2 += __half2float(hp[(long)sb2 * 64 + lane]);
                    tB3 += __half2float(hp[(long)sb3 * 64 + lane]);
                }
                int jA = j, jB = j;
                for (; jA + 4 <= mA; jA += 4) {
                    const int sa0 = els[wv][0][jA + 0], sa1 = els[wv][0][jA + 1];
                    const int sa2 = els[wv][0][jA + 2], sa3 = els[wv][0][jA + 3];
                    tA0 += __half2float(hp[(long)sa0 * 64 + lane]);
                    tA1 += __half2float(hp[(long)sa1 * 64 + lane]);
                    tA2 += __half2float(hp[(long)sa2 * 64 + lane]);
                    tA3 += __half2float(hp[(long)sa3 * 64 + lane]);
                }
                for (; jA < mA; ++jA) tA0 += __half2float(hp[(long)els[wv][0][jA] * 64 + lane]);
                for (; jB + 4 <= mB; jB += 4) {
                    const int sb0 = els[wv][1][jB + 0], sb1 = els[wv][1][jB + 1];
                    const int sb2 = els[wv][1][jB + 2], sb3 = els[wv][1][jB + 3];
                    tB0 += __half2float(hp[(long)sb0 * 64 + lane]);
                    tB1 += __half2float(hp[(long)sb1 * 64 + lane]);
                    tB2 += __half2float(hp[(long)sb2 * 64 + lane]);
                    tB3 += __half2float(hp[(long)sb3 * 64 + lane]);
                }
                for (; jB < mB; ++jB) tB0 += __half2float(hp[(long)els[wv][1][jB] * 64 + lane]);
            }
            accA[i] += (tA0 + tA1) + (tA2 + tA3);
            accB[i] += (tB0 + tB1) + (tB2 + tB3);
        }
    }
    float s = 0.f, s2 = 0.f;
#pragma unroll
    for (int i = 0; i < MAXP; ++i) {
        const int p = p0 + i;
        if (p >= P) continue;
        const int wA = p, wB = p + P;
        const float outA = dis[wA] * accA[i];
        bufh[((long)wA << 6) + lane] = __float2half(outA);
        s += outA;
        s2 = fmaf(outA, outA, s2);
        if (wB < N) {
            const float outB = dis[wB] * accB[i];
            bufh[((long)wB << 6) + lane] = __float2half(outB);
            s += outB;
            s2 = fmaf(outB, outB, s2);
        }
    }
    ls[threadIdx.x] = s;
    ls2[threadIdx.x] = s2;
    __syncthreads();
    if (threadIdx.x < 64) {
        s = ls[lane] + ls[lane + 64] + ls[lane + 128] + ls[lane + 192];
        s2 = ls2[lane] + ls2[lane + 64] + ls2[lane + 128] + ls2[lane + 192];
        unsafeAtomicAdd(&st[lane], s);
        unsafeAtomicAdd(&st[64 + lane], s2);
    }
}

// ----------------------------------------------------- pooling (fused BN+ReLU)
__launch_bounds__(256)
__global__ void k_pool(const __half* __restrict__ x, const int* __restrict__ batch,
                       const float* __restrict__ st, const float* __restrict__ g,
                       const float* __restrict__ be, float* __restrict__ poolsum,
                       float* __restrict__ counts, int N, int npw) {
    const int wid = (blockIdx.x * blockDim.x + threadIdx.x) >> 6;
    const int lane = threadIdx.x & 63;
    const int n0 = wid * npw;
    if (n0 >= N) return;
    const float inv = 1.0f / (float)N;
    const float m = st[lane] * inv;
    const float v = st[64 + lane] * inv - m * m;
    const float sc = g[lane] * rsqrtf(v + EPSBN);
    const float sh = fmaf(-m, sc, be[lane]);
    const int n1 = min(n0 + npw, N);
    float acc = 0.f, cnt = 0.f;
    int gr = batch[n0];
    for (int n = n0; n < n1; ++n) {
        int gn = batch[n];
        if (gn != gr) {
            unsafeAtomicAdd(&poolsum[(long)gr * 64 + lane], acc);
            if (lane == 0) unsafeAtomicAdd(&counts[gr], cnt);
            acc = 0.f;
            cnt = 0.f;
            gr = gn;
        }
        const float val = __half2float(x[((long)n << 6) + lane]);
        acc += fmaxf(fmaf(val, sc, sh), 0.f);
        cnt += 1.f;
    }
    unsafeAtomicAdd(&poolsum[(long)gr * 64 + lane], acc);
    if (lane == 0) unsafeAtomicAdd(&counts[gr], cnt);
}

// --------------------------------------------------------------------- heads
__launch_bounds__(256)
__global__ void k_heads(const float* __restrict__ poolsum, const float* __restrict__ counts,
                        const float* pW1, const float* pb1, const float* pW2, const float* pb2,
                        const float* aW1, const float* ab1, const float* aW2, const float* ab2,
                        const float* tW1, const float* tb1, const float* tW2, const float* tb2,
                        float* __restrict__ out, int G) {
    __shared__ float P[64 * 64];
    __shared__ float Hd[64 * 32];
    const int tid = threadIdx.x;
    for (int i = tid; i < G * 64; i += 256) {
        int g = i >> 6;
        P[i] = poolsum[i] / fmaxf(counts[g], 1.f);
    }
    __syncthreads();
    for (int j = 0; j < 3; ++j) {
        const float* W1 = (j == 0) ? pW1 : (j == 1) ? aW1 : tW1;
        const float* b1 = (j == 0) ? pb1 : (j == 1) ? ab1 : tb1;
        const float* W2 = (j == 0) ? pW2 : (j == 1) ? aW2 : tW2;
        const float* b2 = (j == 0) ? pb2 : (j == 1) ? ab2 : tb2;
        for (int i = tid; i < G * 32; i += 256) {
            int g = i >> 5, k = i & 31;
            float a = b1[k];
#pragma unroll
            for (int c = 0; c < 64; ++c) a = fmaf(P[g * 64 + c], W1[c * 32 + k], a);
            Hd[i] = fmaxf(a, 0.f);
        }
        __syncthreads();
        const int ow = (j == 2) ? 2 : 1;
        const int off = (j == 2) ? 2 : j;
        for (int i = tid; i < G * ow; i += 256) {
            int g = i / ow, o = i - g * ow;
            float a = b2[o];
#pragma unroll
            for (int k = 0; k < 32; ++k) a = fmaf(Hd[g * 32 + k], W2[k * ow + o], a);
            out[g * 4 + off + o] = a;
        }
        __syncthreads();
    }
}

// ====================================================================== host
extern "C" void kernel_launch(void* const* d_in, const int* in_sizes, int n_in,
                              void* d_out, int out_size, void* d_ws, size_t ws_size,
                              hipStream_t stream) {
    const int N = in_sizes[2];      // batch has N entries
    const int E = in_sizes[1] / 2;  // edge_index is [2, E]
    const int G = out_size / 4;     // output [G, 4]

    const float* x0 = (const float*)d_in[0];
    const int* ei = (const int*)d_in[1];
    const int* src = ei;
    const int* dst = ei + E;
    const int* batch = (const int*)d_in[2];

    const float* W[3] = {(const float*)d_in[3], (const float*)d_in[7], (const float*)d_in[11]};
    const float* gam[3] = {(const float*)d_in[5], (const float*)d_in[9], (const float*)d_in[13]};
    const float* bet[3] = {(const float*)d_in[6], (const float*)d_in[10], (const float*)d_in[14]};

    const float* pW1 = (const float*)d_in[15];
    const float* pb1 = (const float*)d_in[16];
    const float* pW2 = (const float*)d_in[17];
    const float* pb2 = (const float*)d_in[18];
    const float* aW1 = (const float*)d_in[19];
    const float* ab1 = (const float*)d_in[20];
    const float* aW2 = (const float*)d_in[21];
    const float* ab2 = (const float*)d_in[22];
    const float* tW1 = (const float*)d_in[23];
    const float* tb1 = (const float*)d_in[24];
    const float* tW2 = (const float*)d_in[25];
    const float* tb2 = (const float*)d_in[26];

    const int C = (E + CHUNK - 1) / CHUNK;   // sort chunks
    const int NB = (N + 127) >> SH;          // coarse buckets
    const int M = NB * C;
    const int wid = (N + 3) >> 2;            // band width (4 bands)
    const float invw = 1.0f / (float)wid;

    // ---- workspace carve (256B aligned)
    auto align = [](size_t x) { return (x + 255) & ~(size_t)255; };
    char* w = (char*)d_ws;
    float* dis = (float*)w;      w += align((size_t)N * 4);
    __half* bufh = (__half*)w;   w += align((size_t)N * 64 * 2);   // fp16 agg out
    __half* hp = (__half*)w;     w += align((size_t)N * 64 * 2);   // fp16 messages
    float* st = (float*)w;       w += align(3 * 128 * 4);
    float* poolsum = (float*)w;  w += align((size_t)G * 64 * 4);
    float* counts = (float*)w;   w += align((size_t)G * 4);
    int* off = (int*)w;          w += align((size_t)(N + 1) * 4);
    int* bnd = (int*)w;          w += align((size_t)N * 4 * 4);    // band starts
    int* hist = (int*)w;         w += align((size_t)M * 4);
    int* bsum = (int*)w;         w += align((size_t)SCANB * 4);
    int* spk = (int*)w;          w += align((size_t)E * 4);
    int* eda = (int*)w;          w += align((size_t)E * 4);
    float4* x0s4 = (float4*)w;   w += align((size_t)N * 16);
    (void)ws_size;

    // ---- CSR build via bucketed counting sort (parallel scan, packed records)
    k_hist<<<C, 1024, 0, stream>>>(dst, hist, E, C, NB);
    k_scanA<<<SCANB, 256, 0, stream>>>(hist, bsum, M);
    k_scanB<<<1, 256, 0, stream>>>(bsum, st, poolsum, counts, G);
    k_scanC<<<SCANB, 256, 0, stream>>>(hist, bsum, off, M, E, N);
    k_sort<<<C, 1024, 0, stream>>>(src, dst, hist, spk, E, C, NB);
    k_csr<<<NB, 256, 0, stream>>>(spk, hist, x0, off, bnd, dis, x0s4, eda, E, C, NB, N, invw);

    // ---- layer 0: fused 3-ch gather + @W0 + BN stats
    k_gl0<<<2048, 256, 0, stream>>>(off, eda, dis, x0s4, W[0], bufh, st, N);

    // ---- layers 1,2: linear then band-outer register-accumulated gather
    const int P = (N + 1) >> 1;
    const int nb_gall = (P + 4 * MAXP - 1) / (4 * MAXP);  // waves*MAXP >= P
    for (int l = 1; l < 3; ++l) {
        k_linear<<<1024, 256, 0, stream>>>(bufh, W[l], st + (l - 1) * 128,
                                           gam[l - 1], bet[l - 1], dis, hp, N);
        k_gall<<<nb_gall, 256, 0, stream>>>(off, bnd, eda, dis, hp, bufh,
                                            st + l * 128, N);
    }

    // ---- global mean pool (BN of layer 2 fused)
    const int npw = 32;
    const int nwaves = (N + npw - 1) / npw;
    const int nb_pool = (nwaves * 64 + 255) / 256;
    k_pool<<<nb_pool, 256, 0, stream>>>(bufh, batch, st + 256, gam[2], bet[2],
                                        poolsum, counts, N, npw);

    // ---- heads
    k_heads<<<1, 256, 0, stream>>>(poolsum, counts, pW1, pb1, pW2, pb2,
                                   aW1, ab1, aW2, ab2, tW1, tb1, tW2, tb2,
                                   (float*)d_out, G);
}

// Round 14
// 473.017 us; speedup vs baseline: 1.8098x; 1.8098x over previous
//
#include <hip/hip_runtime.h>
#include <hip/hip_fp16.h>

#define EPSBN 1e-5f
#define SH 7          // bucket = dst >> SH  (128 nodes per bucket)
#define CHUNK 16384   // edges per sort chunk
#define SCANB 256     // scan blocks

// ------------------------------------------------------- bucketed count sort
// S1: per-chunk histogram over coarse buckets, bucket-major output
__launch_bounds__(1024)
__global__ void k_hist(const int* __restrict__ dst, int* __restrict__ hist,
                       int E, int C, int NB) {
    __shared__ int h[1024];
    const int tid = threadIdx.x, c = blockIdx.x;
    for (int i = tid; i < NB; i += 1024) h[i] = 0;
    __syncthreads();
    const int e0 = c * CHUNK, e1 = min(e0 + CHUNK, E);
    for (int e = e0 + tid; e < e1; e += 1024) atomicAdd(&h[dst[e] >> SH], 1);
    __syncthreads();
    for (int b = tid; b < NB; b += 1024) hist[b * C + c] = h[b];
}

// S2a: per-segment sums
__launch_bounds__(256)
__global__ void k_scanA(const int* __restrict__ hist, int* __restrict__ bsum, int M) {
    __shared__ int part[256];
    const int b = blockIdx.x, t = threadIdx.x;
    const int seg = (M + SCANB - 1) / SCANB;
    const int lo = b * seg, hi = min(lo + seg, M);
    int s = 0;
    for (int i = lo + t; i < hi; i += 256) s += hist[i];
    part[t] = s;
    __syncthreads();
    for (int d = 128; d > 0; d >>= 1) {
        if (t < d) part[t] += part[t + d];
        __syncthreads();
    }
    if (t == 0) bsum[b] = part[0];
}

// S2b: exclusive scan of bsum[SCANB] + zero st/poolsum/counts
__launch_bounds__(256)
__global__ void k_scanB(int* __restrict__ bsum, float* __restrict__ st,
                        float* __restrict__ poolsum, float* __restrict__ counts, int G) {
    __shared__ int sh[256];
    const int t = threadIdx.x;
    sh[t] = bsum[t];
    __syncthreads();
    for (int d = 1; d < 256; d <<= 1) {
        int v = (t >= d) ? sh[t - d] : 0;
        __syncthreads();
        sh[t] += v;
        __syncthreads();
    }
    bsum[t] = (t == 0) ? 0 : sh[t - 1];
    for (int i = t; i < 3 * 128; i += 256) st[i] = 0.f;
    for (int i = t; i < G * 64; i += 256) poolsum[i] = 0.f;
    for (int i = t; i < G; i += 256) counts[i] = 0.f;
}

// S2c: per-segment exclusive scan (in place) + bsum offset; off[N]=E
__launch_bounds__(256)
__global__ void k_scanC(int* __restrict__ hist, const int* __restrict__ bsum,
                        int* __restrict__ off, int M, int E, int N) {
    __shared__ int part[256];
    const int b = blockIdx.x, t = threadIdx.x;
    const int seg = (M + SCANB - 1) / SCANB;
    const int lo = b * seg, hi = min(lo + seg, M);
    const int per = (seg + 255) >> 8;
    const int tl = lo + t * per, th = min(tl + per, hi);
    int s = 0;
    for (int i = tl; i < th; ++i) s += hist[i];
    part[t] = s;
    __syncthreads();
    for (int d = 1; d < 256; d <<= 1) {
        int v = (t >= d) ? part[t - d] : 0;
        __syncthreads();
        part[t] += v;
        __syncthreads();
    }
    int run = bsum[b] + ((t == 0) ? 0 : part[t - 1]);
    for (int i = tl; i < th; ++i) {
        int v = hist[i];
        hist[i] = run;
        run += v;
    }
    if (b == 0 && t == 0) off[N] = E;
}

// S3: scatter packed (dstloc<<18|src) into bucket-grouped order
__launch_bounds__(1024)
__global__ void k_sort(const int* __restrict__ src, const int* __restrict__ dst,
                       const int* __restrict__ hist, int* __restrict__ spk,
                       int E, int C, int NB) {
    __shared__ int cur[1024];
    const int tid = threadIdx.x, c = blockIdx.x;
    for (int b = tid; b < NB; b += 1024) cur[b] = hist[b * C + c];
    __syncthreads();
    const int e0 = c * CHUNK, e1 = min(e0 + CHUNK, E);
    for (int e = e0 + tid; e < e1; e += 1024) {
        const int d = dst[e];
        const int pos = atomicAdd(&cur[d >> SH], 1);
        spk[pos] = ((d & 127) << 18) | src[e];
    }
}

// S4: per bucket -> per-node counts, off[], dis[], x0s4 (prex fused), and eda
__launch_bounds__(256)
__global__ void k_csr(const int* __restrict__ spk, const int* __restrict__ hist,
                      const float* __restrict__ x0, int* __restrict__ off,
                      float* __restrict__ dis, float4* __restrict__ x0s4,
                      int* __restrict__ eda, int E, int C, int NB, int N) {
    __shared__ int cnt_l[128], scn[128];
    const int tid = threadIdx.x, b = blockIdx.x;
    const int node0 = b << SH;
    const int nloc = min(128, N - node0);
    const int ebeg = hist[b * C];
    const int eend = (b + 1 < NB) ? hist[(b + 1) * C] : E;
    if (tid < 128) cnt_l[tid] = 0;
    __syncthreads();
    for (int e = ebeg + tid; e < eend; e += 256) {
        atomicAdd(&cnt_l[spk[e] >> 18], 1);
    }
    __syncthreads();
    if (tid < 128) scn[tid] = cnt_l[tid];
    __syncthreads();
    for (int d = 1; d < 128; d <<= 1) {
        int v = 0;
        if (tid < 128 && tid >= d) v = scn[tid - d];
        __syncthreads();
        if (tid < 128) scn[tid] += v;
        __syncthreads();
    }
    if (tid < nloc) {
        const int excl = scn[tid] - cnt_l[tid];
        const int i = node0 + tid;
        const float d = rsqrtf((float)cnt_l[tid] + 1.0f);
        off[i] = ebeg + excl;
        dis[i] = d;
        x0s4[i] = make_float4(d * x0[3 * i], d * x0[3 * i + 1], d * x0[3 * i + 2], 0.f);
    }
    __syncthreads();
    if (tid < 128) cnt_l[tid] = scn[tid] - cnt_l[tid];  // reuse as cursor
    __syncthreads();
    for (int e = ebeg + tid; e < eend; e += 256) {
        const int p = spk[e];
        const int r = atomicAdd(&cnt_l[p >> 18], 1);
        eda[ebeg + r] = p & 0x3FFFF;
    }
}

// ------------------------- layer 0: gather(3ch) + @W0 + BN stats, all fused
// wave per node: z = dis[w]*(x0s4[w] + sum x0s4[src]); out[c=lane] = z . W0[:,c]
__launch_bounds__(256)
__global__ void k_gl0(const int* __restrict__ off, const int* __restrict__ eda,
                      const float* __restrict__ dis, const float4* __restrict__ x0s4,
                      const float* __restrict__ W0, __half* __restrict__ bufh,
                      float* __restrict__ st, int N) {
    __shared__ float Ws[192];
    __shared__ float ls[256], lq[256];
    const int tid = threadIdx.x;
    const int lane = tid & 63, wv = tid >> 6;
    for (int i = tid; i < 192; i += 256) Ws[i] = W0[i];
    __syncthreads();
    const int nw = gridDim.x * 4;
    float s = 0.f, q = 0.f;
    for (int w = blockIdx.x * 4 + wv; w < N; w += nw) {
        const int e0 = off[w], e1 = off[w + 1];
        float a0 = 0.f, a1 = 0.f, a2 = 0.f;
        for (int e = e0 + lane; e < e1; e += 64) {
            float4 v = x0s4[eda[e]];
            a0 += v.x;
            a1 += v.y;
            a2 += v.z;
        }
#pragma unroll
        for (int d = 32; d; d >>= 1) {
            a0 += __shfl_xor(a0, d);
            a1 += __shfl_xor(a1, d);
            a2 += __shfl_xor(a2, d);
        }
        const float4 sv = x0s4[w];
        const float dw = dis[w];
        const float z0 = dw * (a0 + sv.x), z1 = dw * (a1 + sv.y), z2 = dw * (a2 + sv.z);
        const float val = z0 * Ws[lane] + z1 * Ws[64 + lane] + z2 * Ws[128 + lane];
        bufh[((long)w << 6) + lane] = __float2half(val);
        s += val;
        q = fmaf(val, val, q);
    }
    ls[tid] = s;
    lq[tid] = q;
    __syncthreads();
    if (tid < 64) {
        s = ls[lane] + ls[lane + 64] + ls[lane + 128] + ls[lane + 192];
        q = lq[lane] + lq[lane + 64] + lq[lane + 128] + lq[lane + 192];
        unsafeAtomicAdd(&st[lane], s);
        unsafeAtomicAdd(&st[64 + lane], q);
    }
}

// --------------------------------------------------- fused (BN+ReLU) + linear
// hp = (act(X)(N,64) @ W(64,64)) * dis[row]  stored fp16; X is fp16 input.
// grid-stride over row tiles: W staged once per block.
__launch_bounds__(256)
__global__ void k_linear(const __half* __restrict__ X, const float* __restrict__ W,
                         const float* __restrict__ st, const float* __restrict__ g,
                         const float* __restrict__ be, const float* __restrict__ dis,
                         __half* __restrict__ hp, int N) {
    __shared__ float Ws[64 * 64];
    __shared__ float Xs[32 * 64];
    __shared__ float scs[64], shs[64];
    const int tid = threadIdx.x;
    if (tid < 64) {
        const float inv = 1.0f / (float)N;
        const float m = st[tid] * inv;
        const float v = st[64 + tid] * inv - m * m;
        const float sc = g[tid] * rsqrtf(v + EPSBN);
        scs[tid] = sc;
        shs[tid] = fmaf(-m, sc, be[tid]);
    }
    for (int i = tid; i < 64 * 64; i += 256) Ws[i] = W[i];
    __syncthreads();
    const int c = tid & 63, wv = tid >> 6;
    for (int r0 = blockIdx.x * 32; r0 < N; r0 += gridDim.x * 32) {
        for (int i = tid; i < 32 * 32; i += 256) {  // half2 granules
            const int r = i >> 5, c2 = i & 31;
            const int row = r0 + r;
            float2 f = {0.f, 0.f};
            if (row < N) {
                const __half2 hv = ((const __half2*)X)[((long)row << 5) + c2];
                f = __half22float2(hv);
            }
            const int ch = c2 * 2;
            Xs[r * 64 + ch] = fmaxf(fmaf(f.x, scs[ch], shs[ch]), 0.f);
            Xs[r * 64 + ch + 1] = fmaxf(fmaf(f.y, scs[ch + 1], shs[ch + 1]), 0.f);
        }
        __syncthreads();
        for (int rr = 0; rr < 8; ++rr) {
            const int r = wv * 8 + rr;
            const int row = r0 + r;
            if (row < N) {
                float acc = 0.f;
#pragma unroll
                for (int k = 0; k < 64; ++k) acc = fmaf(Xs[r * 64 + k], Ws[k * 64 + c], acc);
                hp[(long)row * 64 + c] = __float2half(acc * dis[row]);
            }
        }
        __syncthreads();
    }
}

// ------------------------------------------- CSR aggregation + fused BN stats
// 2-node interleave + register-prefetched edge staging.
__launch_bounds__(256)
__global__ void k_gather(const int* __restrict__ off, const int* __restrict__ eda,
                         const float* __restrict__ dis, const __half* __restrict__ hp,
                         __half* __restrict__ aggh, float* __restrict__ st, int N) {
    __shared__ int els[4][2][64];
    __shared__ float ls[256], ls2[256];
    const int lane = threadIdx.x & 63;
    const int wv = threadIdx.x >> 6;
    const int nwaves = gridDim.x * 4;
    const int P = (N + 1) >> 1;
    float s = 0.f, s2 = 0.f;
    for (int p = blockIdx.x * 4 + wv; p < P; p += nwaves) {
        const int wA = p, wB = p + P;
        const bool hasB = (wB < N);
        const int a0o = off[wA];
        const int nA = off[wA + 1] - a0o;
        const int b0o = hasB ? off[wB] : 0;
        const int nB = hasB ? off[wB + 1] - b0o : 0;
        float accA0 = __half2float(hp[(long)wA * 64 + lane]);
        float accA1 = 0.f, accA2 = 0.f, accA3 = 0.f;
        float accB0 = hasB ? __half2float(hp[(long)wB * 64 + lane]) : 0.f;
        float accB1 = 0.f, accB2 = 0.f, accB3 = 0.f;
        // prefetch block 0
        int rA = (lane < nA) ? eda[a0o + lane] : 0;
        int rB = (lane < nB) ? eda[b0o + lane] : 0;
        const int nmax = nA > nB ? nA : nB;
        for (int base = 0; base < nmax; base += 64) {
            els[wv][0][lane] = rA;
            els[wv][1][lane] = rB;
            const int nxt = base + 64;
            if (nxt + lane < nA) rA = eda[a0o + nxt + lane];
            if (nxt + lane < nB) rB = eda[b0o + nxt + lane];
            int mA = nA - base;
            mA = mA < 0 ? 0 : (mA > 64 ? 64 : mA);
            int mB = nB - base;
            mB = mB < 0 ? 0 : (mB > 64 ? 64 : mB);
            const int mc = mA < mB ? mA : mB;
            int j = 0;
            for (; j + 4 <= mc; j += 4) {
                const int sa0 = els[wv][0][j + 0], sa1 = els[wv][0][j + 1];
                const int sa2 = els[wv][0][j + 2], sa3 = els[wv][0][j + 3];
                const int sb0 = els[wv][1][j + 0], sb1 = els[wv][1][j + 1];
                const int sb2 = els[wv][1][j + 2], sb3 = els[wv][1][j + 3];
                const float va0 = __half2float(hp[(long)sa0 * 64 + lane]);
                const float va1 = __half2float(hp[(long)sa1 * 64 + lane]);
                const float va2 = __half2float(hp[(long)sa2 * 64 + lane]);
                const float va3 = __half2float(hp[(long)sa3 * 64 + lane]);
                const float vb0 = __half2float(hp[(long)sb0 * 64 + lane]);
                const float vb1 = __half2float(hp[(long)sb1 * 64 + lane]);
                const float vb2 = __half2float(hp[(long)sb2 * 64 + lane]);
                const float vb3 = __half2float(hp[(long)sb3 * 64 + lane]);
                accA0 += va0;
                accA1 += va1;
                accA2 += va2;
                accA3 += va3;
                accB0 += vb0;
                accB1 += vb1;
                accB2 += vb2;
                accB3 += vb3;
            }
            int jA = j, jB = j;
            for (; jA + 4 <= mA; jA += 4) {
                const int sa0 = els[wv][0][jA + 0], sa1 = els[wv][0][jA + 1];
                const int sa2 = els[wv][0][jA + 2], sa3 = els[wv][0][jA + 3];
                const float va0 = __half2float(hp[(long)sa0 * 64 + lane]);
                const float va1 = __half2float(hp[(long)sa1 * 64 + lane]);
                const float va2 = __half2float(hp[(long)sa2 * 64 + lane]);
                const float va3 = __half2float(hp[(long)sa3 * 64 + lane]);
                accA0 += va0;
                accA1 += va1;
                accA2 += va2;
                accA3 += va3;
            }
            for (; jA < mA; ++jA) accA0 += __half2float(hp[(long)els[wv][0][jA] * 64 + lane]);
            for (; jB + 4 <= mB; jB += 4) {
                const int sb0 = els[wv][1][jB + 0], sb1 = els[wv][1][jB + 1];
                const int sb2 = els[wv][1][jB + 2], sb3 = els[wv][1][jB + 3];
                const float vb0 = __half2float(hp[(long)sb0 * 64 + lane]);
                const float vb1 = __half2float(hp[(long)sb1 * 64 + lane]);
                const float vb2 = __half2float(hp[(long)sb2 * 64 + lane]);
                const float vb3 = __half2float(hp[(long)sb3 * 64 + lane]);
                accB0 += vb0;
                accB1 += vb1;
                accB2 += vb2;
                accB3 += vb3;
            }
            for (; jB < mB; ++jB) accB0 += __half2float(hp[(long)els[wv][1][jB] * 64 + lane]);
        }
        const float outA = dis[wA] * ((accA0 + accA1) + (accA2 + accA3));
        aggh[((long)wA << 6) + lane] = __float2half(outA);
        s += outA;
        s2 = fmaf(outA, outA, s2);
        if (hasB) {
            const float outB = dis[wB] * ((accB0 + accB1) + (accB2 + accB3));
            aggh[((long)wB << 6) + lane] = __float2half(outB);
            s += outB;
            s2 = fmaf(outB, outB, s2);
        }
    }
    ls[threadIdx.x] = s;
    ls2[threadIdx.x] = s2;
    __syncthreads();
    if (threadIdx.x < 64) {
        s = ls[lane] + ls[lane + 64] + ls[lane + 128] + ls[lane + 192];
        s2 = ls2[lane] + ls2[lane + 64] + ls2[lane + 128] + ls2[lane + 192];
        unsafeAtomicAdd(&st[lane], s);
        unsafeAtomicAdd(&st[64 + lane], s2);
    }
}

// ----------------------------------------------------- pooling (fused BN+ReLU)
__launch_bounds__(256)
__global__ void k_pool(const __half* __restrict__ x, const int* __restrict__ batch,
                       const float* __restrict__ st, const float* __restrict__ g,
                       const float* __restrict__ be, float* __restrict__ poolsum,
                       float* __restrict__ counts, int N, int npw) {
    const int wid = (blockIdx.x * blockDim.x + threadIdx.x) >> 6;
    const int lane = threadIdx.x & 63;
    const int n0 = wid * npw;
    if (n0 >= N) return;
    const float inv = 1.0f / (float)N;
    const float m = st[lane] * inv;
    const float v = st[64 + lane] * inv - m * m;
    const float sc = g[lane] * rsqrtf(v + EPSBN);
    const float sh = fmaf(-m, sc, be[lane]);
    const int n1 = min(n0 + npw, N);
    float acc = 0.f, cnt = 0.f;
    int gr = batch[n0];
    for (int n = n0; n < n1; ++n) {
        int gn = batch[n];
        if (gn != gr) {
            unsafeAtomicAdd(&poolsum[(long)gr * 64 + lane], acc);
            if (lane == 0) unsafeAtomicAdd(&counts[gr], cnt);
            acc = 0.f;
            cnt = 0.f;
            gr = gn;
        }
        const float val = __half2float(x[((long)n << 6) + lane]);
        acc += fmaxf(fmaf(val, sc, sh), 0.f);
        cnt += 1.f;
    }
    unsafeAtomicAdd(&poolsum[(long)gr * 64 + lane], acc);
    if (lane == 0) unsafeAtomicAdd(&counts[gr], cnt);
}

// --------------------------------------------------------------------- heads
__launch_bounds__(256)
__global__ void k_heads(const float* __restrict__ poolsum, const float* __restrict__ counts,
                        const float* pW1, const float* pb1, const float* pW2, const float* pb2,
                        const float* aW1, const float* ab1, const float* aW2, const float* ab2,
                        const float* tW1, const float* tb1, const float* tW2, const float* tb2,
                        float* __restrict__ out, int G) {
    __shared__ float P[64 * 64];
    __shared__ float Hd[64 * 32];
    const int tid = threadIdx.x;
    for (int i = tid; i < G * 64; i += 256) {
        int g = i >> 6;
        P[i] = poolsum[i] / fmaxf(counts[g], 1.f);
    }
    __syncthreads();
    for (int j = 0; j < 3; ++j) {
        const float* W1 = (j == 0) ? pW1 : (j == 1) ? aW1 : tW1;
        const float* b1 = (j == 0) ? pb1 : (j == 1) ? ab1 : tb1;
        const float* W2 = (j == 0) ? pW2 : (j == 1) ? aW2 : tW2;
        const float* b2 = (j == 0) ? pb2 : (j == 1) ? ab2 : tb2;
        for (int i = tid; i < G * 32; i += 256) {
            int g = i >> 5, k = i & 31;
            float a = b1[k];
#pragma unroll
            for (int c = 0; c < 64; ++c) a = fmaf(P[g * 64 + c], W1[c * 32 + k], a);
            Hd[i] = fmaxf(a, 0.f);
        }
        __syncthreads();
        const int ow = (j == 2) ? 2 : 1;
        const int off = (j == 2) ? 2 : j;
        for (int i = tid; i < G * ow; i += 256) {
            int g = i / ow, o = i - g * ow;
            float a = b2[o];
#pragma unroll
            for (int k = 0; k < 32; ++k) a = fmaf(Hd[g * 32 + k], W2[k * ow + o], a);
            out[g * 4 + off + o] = a;
        }
        __syncthreads();
    }
}

// ====================================================================== host
extern "C" void kernel_launch(void* const* d_in, const int* in_sizes, int n_in,
                              void* d_out, int out_size, void* d_ws, size_t ws_size,
                              hipStream_t stream) {
    const int N = in_sizes[2];      // batch has N entries
    const int E = in_sizes[1] / 2;  // edge_index is [2, E]
    const int G = out_size / 4;     // output [G, 4]

    const float* x0 = (const float*)d_in[0];
    const int* ei = (const int*)d_in[1];
    const int* src = ei;
    const int* dst = ei + E;
    const int* batch = (const int*)d_in[2];

    const float* W[3] = {(const float*)d_in[3], (const float*)d_in[7], (const float*)d_in[11]};
    const float* gam[3] = {(const float*)d_in[5], (const float*)d_in[9], (const float*)d_in[13]};
    const float* bet[3] = {(const float*)d_in[6], (const float*)d_in[10], (const float*)d_in[14]};

    const float* pW1 = (const float*)d_in[15];
    const float* pb1 = (const float*)d_in[16];
    const float* pW2 = (const float*)d_in[17];
    const float* pb2 = (const float*)d_in[18];
    const float* aW1 = (const float*)d_in[19];
    const float* ab1 = (const float*)d_in[20];
    const float* aW2 = (const float*)d_in[21];
    const float* ab2 = (const float*)d_in[22];
    const float* tW1 = (const float*)d_in[23];
    const float* tb1 = (const float*)d_in[24];
    const float* tW2 = (const float*)d_in[25];
    const float* tb2 = (const float*)d_in[26];

    const int C = (E + CHUNK - 1) / CHUNK;   // sort chunks
    const int NB = (N + 127) >> SH;          // coarse buckets
    const int M = NB * C;

    // ---- workspace carve (256B aligned)
    auto align = [](size_t x) { return (x + 255) & ~(size_t)255; };
    char* w = (char*)d_ws;
    float* dis = (float*)w;      w += align((size_t)N * 4);
    __half* bufh = (__half*)w;   w += align((size_t)N * 64 * 2);   // fp16 agg
    __half* hp = (__half*)w;     w += align((size_t)N * 64 * 2);   // fp16 messages
    float* st = (float*)w;       w += align(3 * 128 * 4);          // st0,st1,st2
    float* poolsum = (float*)w;  w += align((size_t)G * 64 * 4);
    float* counts = (float*)w;   w += align((size_t)G * 4);
    int* off = (int*)w;          w += align((size_t)(N + 1) * 4);
    int* hist = (int*)w;         w += align((size_t)M * 4);
    int* bsum = (int*)w;         w += align((size_t)SCANB * 4);
    int* spk = (int*)w;          w += align((size_t)E * 4);        // packed sort
    int* eda = (int*)w;          w += align((size_t)E * 4);
    float4* x0s4 = (float4*)w;   w += align((size_t)N * 16);
    (void)ws_size;

    const int nb_ga = 2048;

    // ---- CSR build via bucketed counting sort (parallel scan, packed records)
    k_hist<<<C, 1024, 0, stream>>>(dst, hist, E, C, NB);
    k_scanA<<<SCANB, 256, 0, stream>>>(hist, bsum, M);
    k_scanB<<<1, 256, 0, stream>>>(bsum, st, poolsum, counts, G);
    k_scanC<<<SCANB, 256, 0, stream>>>(hist, bsum, off, M, E, N);
    k_sort<<<C, 1024, 0, stream>>>(src, dst, hist, spk, E, C, NB);
    k_csr<<<NB, 256, 0, stream>>>(spk, hist, x0, off, dis, x0s4, eda, E, C, NB, N);

    // ---- layer 0: fused 3-ch gather + @W0 + BN stats
    k_gl0<<<2048, 256, 0, stream>>>(off, eda, dis, x0s4, W[0], bufh, st, N);

    // ---- layers 1,2 (K=64, BN of previous layer fused into staging)
    for (int l = 1; l < 3; ++l) {
        k_linear<<<1024, 256, 0, stream>>>(bufh, W[l], st + (l - 1) * 128,
                                           gam[l - 1], bet[l - 1], dis, hp, N);
        k_gather<<<nb_ga, 256, 0, stream>>>(off, eda, dis, hp, bufh, st + l * 128, N);
    }

    // ---- global mean pool (BN of layer 2 fused)
    const int npw = 32;
    const int nwaves = (N + npw - 1) / npw;
    const int nb_pool = (nwaves * 64 + 255) / 256;
    k_pool<<<nb_pool, 256, 0, stream>>>(bufh, batch, st + 256, gam[2], bet[2],
                                        poolsum, counts, N, npw);

    // ---- heads
    k_heads<<<1, 256, 0, stream>>>(poolsum, counts, pW1, pb1, pW2, pb2,
                                   aW1, ab1, aW2, ab2, tW1, tb1, tW2, tb2,
                                   (float*)d_out, G);
}